// Round 18
// baseline (53.640 us; speedup 1.0000x reference)
//
#include <hip/hip_runtime.h>
#include <hip/hip_bf16.h>

#define N_NODES 4096
#define BATCH 8
#define FEAT 128
#define CAP 256

typedef float v2f __attribute__((ext_vector_type(2)));
typedef short short8 __attribute__((ext_vector_type(8)));
typedef float f32x4 __attribute__((ext_vector_type(4)));

__device__ __forceinline__ unsigned short f2bf(float f) {
    unsigned int u = __float_as_uint(f);
    u += 0x7fffu + ((u >> 16) & 1u);   // RNE (finite, non-NaN here)
    return (unsigned short)(u >> 16);
}

__device__ __forceinline__ unsigned int pk2bf(float a, float b) {
    return (unsigned int)f2bf(a) | ((unsigned int)f2bf(b) << 16);
}

// acc[0..3] (float2 pairs) += p * bf16x8(hv)
__device__ __forceinline__ void fma8v(v2f* acc, v2f pp, uint4 hv) {
    unsigned int u;
    v2f t;
    u = hv.x; t[0] = __uint_as_float(u << 16); t[1] = __uint_as_float(u & 0xffff0000u);
    acc[0] += pp * t;
    u = hv.y; t[0] = __uint_as_float(u << 16); t[1] = __uint_as_float(u & 0xffff0000u);
    acc[1] += pp * t;
    u = hv.z; t[0] = __uint_as_float(u << 16); t[1] = __uint_as_float(u & 0xffff0000u);
    acc[2] += pp * t;
    u = hv.w; t[0] = __uint_as_float(u << 16); t[1] = __uint_as_float(u & 0xffff0000u);
    acc[3] += pp * t;
}

// ---------------------------------------------------------------------------
// K1: bitscan — pure streaming A -> bitmask (grid-stride, no per-row barrier,
// no block churn). Each thread per iter: load 32B (2x float4), write 1 byte
// of sign bits. W transpose-cast distributed over blocks 16..47:
// 32 blocks x 4 waves = 128 n's, ONE WAVE PER N (R17 bug: 256-thread block
// has only 4 waves, so the old *8 indexing left half of Wt poisoned).
// ---------------------------------------------------------------------------
__global__ __launch_bounds__(256) void bitscan(const float* __restrict__ A,
                                               unsigned char* __restrict__ mask,
                                               const float* __restrict__ W,
                                               unsigned short* __restrict__ Wt) {
    int tid = threadIdx.x;
    int bid = blockIdx.x;
    const int nb = N_NODES * N_NODES / 8;   // 2M bytes
    for (int t = bid * 256 + tid; t < nb; t += gridDim.x * 256) {
        const float4* p = (const float4*)(A + (size_t)t * 8);
        float4 v0 = p[0], v1 = p[1];
        unsigned int b = 0;
        b |= (v0.x > 0.f) ? 1u : 0u;
        b |= (v0.y > 0.f) ? 2u : 0u;
        b |= (v0.z > 0.f) ? 4u : 0u;
        b |= (v0.w > 0.f) ? 8u : 0u;
        b |= (v1.x > 0.f) ? 16u : 0u;
        b |= (v1.y > 0.f) ? 32u : 0u;
        b |= (v1.z > 0.f) ? 64u : 0u;
        b |= (v1.w > 0.f) ? 128u : 0u;
        mask[t] = (unsigned char)b;
    }
    // distributed W transpose-cast: blocks 16..47, 4 waves/block, 1 wave/n
    if (bid >= 16 && bid < 48) {
        int n = (bid - 16) * 4 + (tid >> 6);   // 0..127, each exactly once
        int k2 = (tid & 63) * 2;               // lane covers 2 k's
        float w0 = W[(size_t)k2 * FEAT + n];
        float w1 = W[(size_t)(k2 + 1) * FEAT + n];
        *(unsigned int*)(Wt + (size_t)n * FEAT + k2) = pk2bf(w0, w1);
    }
}

// ---------------------------------------------------------------------------
// K2: listbuild — bitmask -> neighbor lists. One wave per row: lane l reads
// one u64 (cols 64l..64l+63; 512B/wave, L2-hot), popc + shfl prefix-sum,
// then serially expands its ~0-3 set bits (ctz loop). Ascending order.
// ---------------------------------------------------------------------------
__global__ __launch_bounds__(256) void listbuild(const unsigned char* __restrict__ mask,
                                                 unsigned short* __restrict__ nbr,
                                                 int* __restrict__ deg) {
    int tid = threadIdx.x;
    int lane = tid & 63;
    int row = blockIdx.x * 4 + (tid >> 6);

    unsigned long long bits = ((const unsigned long long*)mask)[(size_t)row * 64 + lane];
    int pc = (int)__popcll(bits);
    int pre = pc;
#pragma unroll
    for (int off = 1; off < 64; off <<= 1) {
        int v = __shfl_up(pre, off);
        if (lane >= off) pre += v;
    }
    int total = __shfl(pre, 63);
    int pos = pre - pc;                 // exclusive prefix
    unsigned short* lst = nbr + (size_t)row * CAP;
    unsigned long long b = bits;
    int colbase = lane << 6;
    while (b) {
        int j = __builtin_ctzll(b);
        b &= b - 1;
        if (pos < CAP) lst[pos] = (unsigned short)(colbase + j);
        ++pos;
    }
    if (lane == 0) deg[row] = total < CAP ? total : CAP;
}

// ---------------------------------------------------------------------------
// K3: h = x @ Wt^T via MFMA 16x16x32 bf16, LDS-staged (R13, verified).
// x-tile coalesced f32 -> bf16 -> swizzled LDS; Wt (L2-hot) -> swizzled LDS.
// Fragment ds_reads use XOR swizzle kb ^ ((row&7)<<4) (G4; row&7 == ln&7).
// Fragment layout (gfx950, m89-verified): A/B elems 0-3 <-> k=(lane>>4)*4+j,
// elems 4-7 <-> k=16+..., m/n = lane&15; C/D col=lane&15, row=(lane>>4)*4+r.
// ---------------------------------------------------------------------------
__global__ __launch_bounds__(256) void gemm_mfma(const float* __restrict__ x,
                                                 const unsigned short* __restrict__ Wt,
                                                 const float* __restrict__ a_src,
                                                 const float* __restrict__ a_dst,
                                                 unsigned short* __restrict__ h,
                                                 float* __restrict__ es,
                                                 float* __restrict__ ed) {
    __shared__ unsigned short xs[64 * FEAT];    // 16 KB, swizzled bf16 x-tile
    __shared__ unsigned short wsh[FEAT * FEAT]; // 32 KB, swizzled bf16 Wt

    int tid = threadIdx.x;
    int lane = tid & 63;
    int w = tid >> 6;
    int ln = lane & 15;
    int kg = lane >> 4;              // 0..3
    int m0 = blockIdx.x * 64;

#pragma unroll
    for (int it = 0; it < 16; ++it) {
        int idx = it * 256 + tid;        // 0..4095
        int n = idx >> 5, c = idx & 31;  // chunk c covers kb = c*8 .. +8
        uint2 v = *(const uint2*)(Wt + (size_t)n * FEAT + c * 4);
        int kb = (c * 8) ^ ((n & 7) << 4);
        *(uint2*)((char*)wsh + n * 256 + kb) = v;
    }
#pragma unroll
    for (int it = 0; it < 8; ++it) {
        int idx = it * 256 + tid;        // 0..2047
        int r = idx >> 5, c = idx & 31;
        float4 v = *(const float4*)(x + (size_t)(m0 + r) * FEAT + c * 4);
        uint2 p; p.x = pk2bf(v.x, v.y); p.y = pk2bf(v.z, v.w);
        int kb = (c * 8) ^ ((r & 7) << 4);
        *(uint2*)((char*)xs + r * 256 + kb) = p;
    }
    __syncthreads();

    union frag { short8 s; uint u[4]; };
    int sw = (ln & 7) << 4;              // per-lane swizzle constant

    f32x4 acc[8];
#pragma unroll
    for (int t = 0; t < 8; ++t) acc[t] = (f32x4)(0.f);

    int ra = w * 16 + ln;                // a-frag LDS row
#pragma unroll
    for (int ks = 0; ks < 4; ++ks) {
        int klo = (ks * 64 + kg * 8) ^ sw;
        int khi = (ks * 64 + 32 + kg * 8) ^ sw;
        frag af;
        {
            uint2 lo = *(const uint2*)((const char*)xs + ra * 256 + klo);
            uint2 hi = *(const uint2*)((const char*)xs + ra * 256 + khi);
            af.u[0] = lo.x; af.u[1] = lo.y; af.u[2] = hi.x; af.u[3] = hi.y;
        }
#pragma unroll
        for (int t = 0; t < 8; ++t) {
            int n = t * 16 + ln;
            frag bf;
            uint2 lo = *(const uint2*)((const char*)wsh + n * 256 + klo);
            uint2 hi = *(const uint2*)((const char*)wsh + n * 256 + khi);
            bf.u[0] = lo.x; bf.u[1] = lo.y; bf.u[2] = hi.x; bf.u[3] = hi.y;
            acc[t] = __builtin_amdgcn_mfma_f32_16x16x32_bf16(af.s, bf.s, acc[t], 0, 0, 0);
        }
    }

    float as8[8], ad8[8];
#pragma unroll
    for (int t = 0; t < 8; ++t) { as8[t] = a_src[t * 16 + ln]; ad8[t] = a_dst[t * 16 + ln]; }

#pragma unroll
    for (int r = 0; r < 4; ++r) {
        int m = m0 + w * 16 + kg * 4 + r;
        float ps = 0.f, pd = 0.f;
#pragma unroll
        for (int t = 0; t < 8; ++t) {
            float vv = acc[t][r];
            h[(size_t)m * FEAT + t * 16 + ln] = f2bf(vv);
            ps += vv * as8[t];
            pd += vv * ad8[t];
        }
#pragma unroll
        for (int off = 8; off >= 1; off >>= 1) {
            ps += __shfl_xor(ps, off);
            pd += __shfl_xor(pd, off);
        }
        if (ln == 0) { es[m] = ps; ed[m] = pd; }
    }
}

// ---------------------------------------------------------------------------
// K4: aggregate (unchanged): one wave per (b,i); reg-cached z/col; 8 nbrs/iter
// (4 groups x 2 chains), 8 bf16 cols/lane as uint4, packed-f32 FMA.
// blockIdx&7 = batch -> XCD/L2 affinity for the 1MB h[b] slice.
// ---------------------------------------------------------------------------
__global__ __launch_bounds__(256) void aggregate(const unsigned short* __restrict__ h,
                                                 const float* __restrict__ es,
                                                 const float* __restrict__ ed,
                                                 const unsigned short* __restrict__ nbr,
                                                 const int* __restrict__ deg,
                                                 const float* __restrict__ bias,
                                                 float* __restrict__ out) {
    int lane = threadIdx.x & 63;
    int g = lane >> 4;
    int c8 = (lane & 15) * 8;
    int b = blockIdx.x & 7;
    int i = (blockIdx.x >> 3) * 4 + (threadIdx.x >> 6);

    int d = deg[i];
    const unsigned short* lst = nbr + (size_t)i * CAP;
    float esv = es[b * N_NODES + i];
    const float* edb = ed + b * N_NODES;

    float zv0 = -1e30f, zv1 = -1e30f, zv2 = -1e30f, zv3 = -1e30f;
    int cv0 = 0, cv1 = 0, cv2 = 0, cv3 = 0;
    float m = -1e30f;
#define PASS1(c, zz, cc)                                            \
    if (c * 64 < d) {                                               \
        int j = c * 64 + lane;                                      \
        if (j < d) {                                                \
            cc = lst[j];                                            \
            float z0 = esv + edb[cc];                               \
            zz = z0 > 0.f ? z0 : 0.2f * z0;                         \
        }                                                           \
        m = fmaxf(m, zz);                                           \
    }
    PASS1(0, zv0, cv0)
    PASS1(1, zv1, cv1)
    PASS1(2, zv2, cv2)
    PASS1(3, zv3, cv3)
#undef PASS1
#pragma unroll
    for (int off = 32; off >= 1; off >>= 1) m = fmaxf(m, __shfl_xor(m, off));

    const unsigned short* hb = h + (size_t)b * N_NODES * FEAT;
    v2f acc0[4], acc1[4];
#pragma unroll
    for (int k = 0; k < 4; ++k) { acc0[k] = (v2f)(0.f); acc1[k] = (v2f)(0.f); }
    float s = 0.f;
#define PASS2(c, zz, cc)                                                        \
    if (c * 64 < d) {                                                           \
        float p = __expf(zz - m);                                               \
        s += p;                                                                 \
        int n = d - c * 64; if (n > 64) n = 64;                                 \
        int nn = (n + 7) & ~7;                                                  \
        for (int jj = 0; jj < nn; jj += 8) {                                    \
            int j0 = jj + g, j1 = jj + 4 + g;                                   \
            float p0 = __shfl(p, j0); int cj0 = __shfl(cc, j0);                 \
            float p1 = __shfl(p, j1); int cj1 = __shfl(cc, j1);                 \
            uint4 h0 = *(const uint4*)(hb + (size_t)cj0 * FEAT + c8);           \
            uint4 h1 = *(const uint4*)(hb + (size_t)cj1 * FEAT + c8);           \
            v2f pp0; pp0[0] = p0; pp0[1] = p0;                                  \
            v2f pp1; pp1[0] = p1; pp1[1] = p1;                                  \
            fma8v(acc0, pp0, h0);                                               \
            fma8v(acc1, pp1, h1);                                               \
        }                                                                       \
    }
    PASS2(0, zv0, cv0)
    PASS2(1, zv1, cv1)
    PASS2(2, zv2, cv2)
    PASS2(3, zv3, cv3)
#undef PASS2

#pragma unroll
    for (int off = 32; off >= 1; off >>= 1) s += __shfl_xor(s, off);
    float inv = 1.0f / s;

#pragma unroll
    for (int k = 0; k < 4; ++k) acc0[k] += acc1[k];
#pragma unroll
    for (int k = 0; k < 4; ++k) {
        acc0[k][0] += __shfl_xor(acc0[k][0], 16);
        acc0[k][1] += __shfl_xor(acc0[k][1], 16);
        acc0[k][0] += __shfl_xor(acc0[k][0], 32);
        acc0[k][1] += __shfl_xor(acc0[k][1], 32);
    }

    if (lane < 16) {
        float4 b0 = *(const float4*)(bias + c8);
        float4 b1 = *(const float4*)(bias + c8 + 4);
        float o[8];
        o[0] = acc0[0][0] * inv + b0.x; o[1] = acc0[0][1] * inv + b0.y;
        o[2] = acc0[1][0] * inv + b0.z; o[3] = acc0[1][1] * inv + b0.w;
        o[4] = acc0[2][0] * inv + b1.x; o[5] = acc0[2][1] * inv + b1.y;
        o[6] = acc0[3][0] * inv + b1.z; o[7] = acc0[3][1] * inv + b1.w;
#pragma unroll
        for (int k = 0; k < 8; ++k) o[k] = o[k] > 0.f ? o[k] : 0.3f * o[k];
        float* orow = out + ((size_t)b * N_NODES + i) * FEAT + c8;
        *(float4*)orow = make_float4(o[0], o[1], o[2], o[3]);
        *(float4*)(orow + 4) = make_float4(o[4], o[5], o[6], o[7]);
    }
}

// ---------------------------------------------------------------------------
extern "C" void kernel_launch(void* const* d_in, const int* in_sizes, int n_in,
                              void* d_out, int out_size, void* d_ws, size_t ws_size,
                              hipStream_t stream) {
    const float* x     = (const float*)d_in[0];
    const float* A     = (const float*)d_in[1];
    const float* W     = (const float*)d_in[2];
    const float* bias  = (const float*)d_in[3];
    const float* a_src = (const float*)d_in[4];
    const float* a_dst = (const float*)d_in[5];
    float* out = (float*)d_out;

    // workspace layout (~13 MB)
    char* ws = (char*)d_ws;
    unsigned short* h  = (unsigned short*)ws;                   // B*N*C bf16 (8.39 MB)
    float* es = (float*)(h + (size_t)BATCH * N_NODES * FEAT);   // B*N f32
    float* ed = es + BATCH * N_NODES;                           // B*N f32
    unsigned short* Wt = (unsigned short*)(ed + BATCH * N_NODES); // F*C bf16 (32 KB)
    int* dg = (int*)(Wt + FEAT * FEAT);                         // N ints
    unsigned short* nb = (unsigned short*)(dg + N_NODES);       // N*CAP (2 MB)
    unsigned char* mk = (unsigned char*)(nb + (size_t)N_NODES * CAP); // N*N/8 (2 MB)

    hipLaunchKernelGGL(bitscan, dim3(2048), dim3(256), 0, stream, A, mk, W, Wt);
    hipLaunchKernelGGL(listbuild, dim3(N_NODES / 4), dim3(256), 0, stream, mk, nb, dg);
    hipLaunchKernelGGL(gemm_mfma, dim3(BATCH * N_NODES / 64), dim3(256), 0, stream,
                       x, Wt, a_src, a_dst, h, es, ed);
    hipLaunchKernelGGL(aggregate, dim3(BATCH * N_NODES / 4), dim3(256), 0, stream,
                       h, es, ed, nb, dg, bias, out);
}

// Round 19
// 53.485 us; speedup vs baseline: 1.0029x; 1.0029x over previous
//
#include <hip/hip_runtime.h>
#include <hip/hip_bf16.h>

#define N_NODES 4096
#define BATCH 8
#define FEAT 128
#define CAP 256

typedef float v2f __attribute__((ext_vector_type(2)));
typedef short short8 __attribute__((ext_vector_type(8)));
typedef float f32x4 __attribute__((ext_vector_type(4)));

__device__ __forceinline__ unsigned short f2bf(float f) {
    unsigned int u = __float_as_uint(f);
    u += 0x7fffu + ((u >> 16) & 1u);   // RNE (finite, non-NaN here)
    return (unsigned short)(u >> 16);
}

__device__ __forceinline__ unsigned int pk2bf(float a, float b) {
    return (unsigned int)f2bf(a) | ((unsigned int)f2bf(b) << 16);
}

// acc[0..3] (float2 pairs) += p * bf16x8(hv)
__device__ __forceinline__ void fma8v(v2f* acc, v2f pp, uint4 hv) {
    unsigned int u;
    v2f t;
    u = hv.x; t[0] = __uint_as_float(u << 16); t[1] = __uint_as_float(u & 0xffff0000u);
    acc[0] += pp * t;
    u = hv.y; t[0] = __uint_as_float(u << 16); t[1] = __uint_as_float(u & 0xffff0000u);
    acc[1] += pp * t;
    u = hv.z; t[0] = __uint_as_float(u << 16); t[1] = __uint_as_float(u & 0xffff0000u);
    acc[2] += pp * t;
    u = hv.w; t[0] = __uint_as_float(u << 16); t[1] = __uint_as_float(u & 0xffff0000u);
    acc[3] += pp * t;
}

// ---------------------------------------------------------------------------
// K1: bitscan — ballot-mask streaming. Per wave-iter: 64 lanes read one
// float4 each (1KB coalesced), 4 ballots pack 256 sign bits into 4 u64
// (SALU), lane 0 stores them as 2x 16B dword4 stores. NO per-lane byte/short
// stores (the sub-dword scattered stores that both prior scan shapes shared
// — the last structural difference vs the 6.7 TB/s fill kernel).
// Mask is component-permuted: word (s*4+c) of a row covers cols 256s+4j+c.
// W transpose-cast distributed over blocks 16..47 (R18-verified).
// ---------------------------------------------------------------------------
__global__ __launch_bounds__(256) void bitscan(const float* __restrict__ A,
                                               unsigned long long* __restrict__ maskw,
                                               const float* __restrict__ W,
                                               unsigned short* __restrict__ Wt) {
    int tid = threadIdx.x;
    int bid = blockIdx.x;
    int lane = tid & 63;
    int w = tid >> 6;
    int gw = bid * 4 + w;              // 0..8191 (2048 blocks x 4 waves)

#pragma unroll
    for (int it = 0; it < 8; ++it) {
        int t = gw * 8 + it;           // 0..65535 wave-tiles of 256 floats
        float4 v = *(const float4*)(A + (size_t)t * 256 + lane * 4);
        unsigned long long m0 = __ballot(v.x > 0.f);
        unsigned long long m1 = __ballot(v.y > 0.f);
        unsigned long long m2 = __ballot(v.z > 0.f);
        unsigned long long m3 = __ballot(v.w > 0.f);
        if (lane == 0) {
            unsigned long long* q = maskw + (size_t)t * 4;
            ulonglong2 a; a.x = m0; a.y = m1;
            ulonglong2 b; b.x = m2; b.y = m3;
            *(ulonglong2*)q = a;
            *(ulonglong2*)(q + 2) = b;
        }
    }

    // distributed W transpose-cast: blocks 16..47, 4 waves/block, 1 wave/n
    if (bid >= 16 && bid < 48) {
        int n = (bid - 16) * 4 + w;        // 0..127, each exactly once
        int k2 = lane * 2;                 // lane covers 2 k's
        float w0 = W[(size_t)k2 * FEAT + n];
        float w1 = W[(size_t)(k2 + 1) * FEAT + n];
        *(unsigned int*)(Wt + (size_t)n * FEAT + k2) = pk2bf(w0, w1);
    }
}

// ---------------------------------------------------------------------------
// K2: listbuild — permuted bitmask -> neighbor lists. One wave per row:
// lane l reads word row*64+l; that word covers cols 256*(l>>2) + 4*j + (l&3)
// for set bit j. popc + shfl prefix-sum, ctz expand. List order is permuted
// vs ascending — softmax/aggregation are order-independent up to FP rounding.
// ---------------------------------------------------------------------------
__global__ __launch_bounds__(256) void listbuild(const unsigned long long* __restrict__ maskw,
                                                 unsigned short* __restrict__ nbr,
                                                 int* __restrict__ deg) {
    int tid = threadIdx.x;
    int lane = tid & 63;
    int row = blockIdx.x * 4 + (tid >> 6);

    unsigned long long bits = maskw[(size_t)row * 64 + lane];
    int pc = (int)__popcll(bits);
    int pre = pc;
#pragma unroll
    for (int off = 1; off < 64; off <<= 1) {
        int v = __shfl_up(pre, off);
        if (lane >= off) pre += v;
    }
    int total = __shfl(pre, 63);
    int pos = pre - pc;                 // exclusive prefix
    unsigned short* lst = nbr + (size_t)row * CAP;
    unsigned long long b = bits;
    int colbase = ((lane >> 2) << 8) | (lane & 3);
    while (b) {
        int j = __builtin_ctzll(b);
        b &= b - 1;
        if (pos < CAP) lst[pos] = (unsigned short)(colbase + 4 * j);
        ++pos;
    }
    if (lane == 0) deg[row] = total < CAP ? total : CAP;
}

// ---------------------------------------------------------------------------
// K3: h = x @ Wt^T via MFMA 16x16x32 bf16, LDS-staged (R13, verified).
// x-tile coalesced f32 -> bf16 -> swizzled LDS; Wt (L2-hot) -> swizzled LDS.
// Fragment ds_reads use XOR swizzle kb ^ ((row&7)<<4) (G4; row&7 == ln&7).
// Fragment layout (gfx950, m89-verified): A/B elems 0-3 <-> k=(lane>>4)*4+j,
// elems 4-7 <-> k=16+..., m/n = lane&15; C/D col=lane&15, row=(lane>>4)*4+r.
// ---------------------------------------------------------------------------
__global__ __launch_bounds__(256) void gemm_mfma(const float* __restrict__ x,
                                                 const unsigned short* __restrict__ Wt,
                                                 const float* __restrict__ a_src,
                                                 const float* __restrict__ a_dst,
                                                 unsigned short* __restrict__ h,
                                                 float* __restrict__ es,
                                                 float* __restrict__ ed) {
    __shared__ unsigned short xs[64 * FEAT];    // 16 KB, swizzled bf16 x-tile
    __shared__ unsigned short wsh[FEAT * FEAT]; // 32 KB, swizzled bf16 Wt

    int tid = threadIdx.x;
    int lane = tid & 63;
    int w = tid >> 6;
    int ln = lane & 15;
    int kg = lane >> 4;              // 0..3
    int m0 = blockIdx.x * 64;

#pragma unroll
    for (int it = 0; it < 16; ++it) {
        int idx = it * 256 + tid;        // 0..4095
        int n = idx >> 5, c = idx & 31;  // chunk c covers kb = c*8 .. +8
        uint2 v = *(const uint2*)(Wt + (size_t)n * FEAT + c * 4);
        int kb = (c * 8) ^ ((n & 7) << 4);
        *(uint2*)((char*)wsh + n * 256 + kb) = v;
    }
#pragma unroll
    for (int it = 0; it < 8; ++it) {
        int idx = it * 256 + tid;        // 0..2047
        int r = idx >> 5, c = idx & 31;
        float4 v = *(const float4*)(x + (size_t)(m0 + r) * FEAT + c * 4);
        uint2 p; p.x = pk2bf(v.x, v.y); p.y = pk2bf(v.z, v.w);
        int kb = (c * 8) ^ ((r & 7) << 4);
        *(uint2*)((char*)xs + r * 256 + kb) = p;
    }
    __syncthreads();

    union frag { short8 s; uint u[4]; };
    int sw = (ln & 7) << 4;              // per-lane swizzle constant

    f32x4 acc[8];
#pragma unroll
    for (int t = 0; t < 8; ++t) acc[t] = (f32x4)(0.f);

    int ra = w * 16 + ln;                // a-frag LDS row
#pragma unroll
    for (int ks = 0; ks < 4; ++ks) {
        int klo = (ks * 64 + kg * 8) ^ sw;
        int khi = (ks * 64 + 32 + kg * 8) ^ sw;
        frag af;
        {
            uint2 lo = *(const uint2*)((const char*)xs + ra * 256 + klo);
            uint2 hi = *(const uint2*)((const char*)xs + ra * 256 + khi);
            af.u[0] = lo.x; af.u[1] = lo.y; af.u[2] = hi.x; af.u[3] = hi.y;
        }
#pragma unroll
        for (int t = 0; t < 8; ++t) {
            int n = t * 16 + ln;
            frag bf;
            uint2 lo = *(const uint2*)((const char*)wsh + n * 256 + klo);
            uint2 hi = *(const uint2*)((const char*)wsh + n * 256 + khi);
            bf.u[0] = lo.x; bf.u[1] = lo.y; bf.u[2] = hi.x; bf.u[3] = hi.y;
            acc[t] = __builtin_amdgcn_mfma_f32_16x16x32_bf16(af.s, bf.s, acc[t], 0, 0, 0);
        }
    }

    float as8[8], ad8[8];
#pragma unroll
    for (int t = 0; t < 8; ++t) { as8[t] = a_src[t * 16 + ln]; ad8[t] = a_dst[t * 16 + ln]; }

#pragma unroll
    for (int r = 0; r < 4; ++r) {
        int m = m0 + w * 16 + kg * 4 + r;
        float ps = 0.f, pd = 0.f;
#pragma unroll
        for (int t = 0; t < 8; ++t) {
            float vv = acc[t][r];
            h[(size_t)m * FEAT + t * 16 + ln] = f2bf(vv);
            ps += vv * as8[t];
            pd += vv * ad8[t];
        }
#pragma unroll
        for (int off = 8; off >= 1; off >>= 1) {
            ps += __shfl_xor(ps, off);
            pd += __shfl_xor(pd, off);
        }
        if (ln == 0) { es[m] = ps; ed[m] = pd; }
    }
}

// ---------------------------------------------------------------------------
// K4: aggregate (unchanged): one wave per (b,i); reg-cached z/col; 8 nbrs/iter
// (4 groups x 2 chains), 8 bf16 cols/lane as uint4, packed-f32 FMA.
// blockIdx&7 = batch -> XCD/L2 affinity for the 1MB h[b] slice.
// ---------------------------------------------------------------------------
__global__ __launch_bounds__(256) void aggregate(const unsigned short* __restrict__ h,
                                                 const float* __restrict__ es,
                                                 const float* __restrict__ ed,
                                                 const unsigned short* __restrict__ nbr,
                                                 const int* __restrict__ deg,
                                                 const float* __restrict__ bias,
                                                 float* __restrict__ out) {
    int lane = threadIdx.x & 63;
    int g = lane >> 4;
    int c8 = (lane & 15) * 8;
    int b = blockIdx.x & 7;
    int i = (blockIdx.x >> 3) * 4 + (threadIdx.x >> 6);

    int d = deg[i];
    const unsigned short* lst = nbr + (size_t)i * CAP;
    float esv = es[b * N_NODES + i];
    const float* edb = ed + b * N_NODES;

    float zv0 = -1e30f, zv1 = -1e30f, zv2 = -1e30f, zv3 = -1e30f;
    int cv0 = 0, cv1 = 0, cv2 = 0, cv3 = 0;
    float m = -1e30f;
#define PASS1(c, zz, cc)                                            \
    if (c * 64 < d) {                                               \
        int j = c * 64 + lane;                                      \
        if (j < d) {                                                \
            cc = lst[j];                                            \
            float z0 = esv + edb[cc];                               \
            zz = z0 > 0.f ? z0 : 0.2f * z0;                         \
        }                                                           \
        m = fmaxf(m, zz);                                           \
    }
    PASS1(0, zv0, cv0)
    PASS1(1, zv1, cv1)
    PASS1(2, zv2, cv2)
    PASS1(3, zv3, cv3)
#undef PASS1
#pragma unroll
    for (int off = 32; off >= 1; off >>= 1) m = fmaxf(m, __shfl_xor(m, off));

    const unsigned short* hb = h + (size_t)b * N_NODES * FEAT;
    v2f acc0[4], acc1[4];
#pragma unroll
    for (int k = 0; k < 4; ++k) { acc0[k] = (v2f)(0.f); acc1[k] = (v2f)(0.f); }
    float s = 0.f;
#define PASS2(c, zz, cc)                                                        \
    if (c * 64 < d) {                                                           \
        float p = __expf(zz - m);                                               \
        s += p;                                                                 \
        int n = d - c * 64; if (n > 64) n = 64;                                 \
        int nn = (n + 7) & ~7;                                                  \
        for (int jj = 0; jj < nn; jj += 8) {                                    \
            int j0 = jj + g, j1 = jj + 4 + g;                                   \
            float p0 = __shfl(p, j0); int cj0 = __shfl(cc, j0);                 \
            float p1 = __shfl(p, j1); int cj1 = __shfl(cc, j1);                 \
            uint4 h0 = *(const uint4*)(hb + (size_t)cj0 * FEAT + c8);           \
            uint4 h1 = *(const uint4*)(hb + (size_t)cj1 * FEAT + c8);           \
            v2f pp0; pp0[0] = p0; pp0[1] = p0;                                  \
            v2f pp1; pp1[0] = p1; pp1[1] = p1;                                  \
            fma8v(acc0, pp0, h0);                                               \
            fma8v(acc1, pp1, h1);                                               \
        }                                                                       \
    }
    PASS2(0, zv0, cv0)
    PASS2(1, zv1, cv1)
    PASS2(2, zv2, cv2)
    PASS2(3, zv3, cv3)
#undef PASS2

#pragma unroll
    for (int off = 32; off >= 1; off >>= 1) s += __shfl_xor(s, off);
    float inv = 1.0f / s;

#pragma unroll
    for (int k = 0; k < 4; ++k) acc0[k] += acc1[k];
#pragma unroll
    for (int k = 0; k < 4; ++k) {
        acc0[k][0] += __shfl_xor(acc0[k][0], 16);
        acc0[k][1] += __shfl_xor(acc0[k][1], 16);
        acc0[k][0] += __shfl_xor(acc0[k][0], 32);
        acc0[k][1] += __shfl_xor(acc0[k][1], 32);
    }

    if (lane < 16) {
        float4 b0 = *(const float4*)(bias + c8);
        float4 b1 = *(const float4*)(bias + c8 + 4);
        float o[8];
        o[0] = acc0[0][0] * inv + b0.x; o[1] = acc0[0][1] * inv + b0.y;
        o[2] = acc0[1][0] * inv + b0.z; o[3] = acc0[1][1] * inv + b0.w;
        o[4] = acc0[2][0] * inv + b1.x; o[5] = acc0[2][1] * inv + b1.y;
        o[6] = acc0[3][0] * inv + b1.z; o[7] = acc0[3][1] * inv + b1.w;
#pragma unroll
        for (int k = 0; k < 8; ++k) o[k] = o[k] > 0.f ? o[k] : 0.3f * o[k];
        float* orow = out + ((size_t)b * N_NODES + i) * FEAT + c8;
        *(float4*)orow = make_float4(o[0], o[1], o[2], o[3]);
        *(float4*)(orow + 4) = make_float4(o[4], o[5], o[6], o[7]);
    }
}

// ---------------------------------------------------------------------------
extern "C" void kernel_launch(void* const* d_in, const int* in_sizes, int n_in,
                              void* d_out, int out_size, void* d_ws, size_t ws_size,
                              hipStream_t stream) {
    const float* x     = (const float*)d_in[0];
    const float* A     = (const float*)d_in[1];
    const float* W     = (const float*)d_in[2];
    const float* bias  = (const float*)d_in[3];
    const float* a_src = (const float*)d_in[4];
    const float* a_dst = (const float*)d_in[5];
    float* out = (float*)d_out;

    // workspace layout (~13 MB)
    char* ws = (char*)d_ws;
    unsigned short* h  = (unsigned short*)ws;                   // B*N*C bf16 (8.39 MB)
    float* es = (float*)(h + (size_t)BATCH * N_NODES * FEAT);   // B*N f32
    float* ed = es + BATCH * N_NODES;                           // B*N f32
    unsigned short* Wt = (unsigned short*)(ed + BATCH * N_NODES); // F*C bf16 (32 KB)
    int* dg = (int*)(Wt + FEAT * FEAT);                         // N ints
    unsigned short* nb = (unsigned short*)(dg + N_NODES);       // N*CAP (2 MB)
    unsigned long long* mk = (unsigned long long*)(nb + (size_t)N_NODES * CAP); // N*N/64 u64 (2 MB)

    hipLaunchKernelGGL(bitscan, dim3(2048), dim3(256), 0, stream, A, mk, W, Wt);
    hipLaunchKernelGGL(listbuild, dim3(N_NODES / 4), dim3(256), 0, stream, mk, nb, dg);
    hipLaunchKernelGGL(gemm_mfma, dim3(BATCH * N_NODES / 64), dim3(256), 0, stream,
                       x, Wt, a_src, a_dst, h, es, ed);
    hipLaunchKernelGGL(aggregate, dim3(BATCH * N_NODES / 4), dim3(256), 0, stream,
                       h, es, ed, nb, dg, bias, out);
}

// Round 20
// 50.736 us; speedup vs baseline: 1.0572x; 1.0542x over previous
//
#include <hip/hip_runtime.h>
#include <hip/hip_bf16.h>

#define N_NODES 4096
#define BATCH 8
#define FEAT 128
#define CAP 256

typedef float v2f __attribute__((ext_vector_type(2)));
typedef short short8 __attribute__((ext_vector_type(8)));
typedef float f32x4 __attribute__((ext_vector_type(4)));

__device__ __forceinline__ unsigned short f2bf(float f) {
    unsigned int u = __float_as_uint(f);
    u += 0x7fffu + ((u >> 16) & 1u);   // RNE (finite, non-NaN here)
    return (unsigned short)(u >> 16);
}

__device__ __forceinline__ unsigned int pk2bf(float a, float b) {
    return (unsigned int)f2bf(a) | ((unsigned int)f2bf(b) << 16);
}

// acc[0..3] (float2 pairs) += p * bf16x8(hv)
__device__ __forceinline__ void fma8v(v2f* acc, v2f pp, uint4 hv) {
    unsigned int u;
    v2f t;
    u = hv.x; t[0] = __uint_as_float(u << 16); t[1] = __uint_as_float(u & 0xffff0000u);
    acc[0] += pp * t;
    u = hv.y; t[0] = __uint_as_float(u << 16); t[1] = __uint_as_float(u & 0xffff0000u);
    acc[1] += pp * t;
    u = hv.z; t[0] = __uint_as_float(u << 16); t[1] = __uint_as_float(u & 0xffff0000u);
    acc[2] += pp * t;
    u = hv.w; t[0] = __uint_as_float(u << 16); t[1] = __uint_as_float(u & 0xffff0000u);
    acc[3] += pp * t;
}

// ---------------------------------------------------------------------------
// K1: A-scan, one block per row, 512 threads = 8 waves (champion config,
// R16-measured 50.7us total). Wave w scans cols [512w, 512w+512): 2 float4
// per lane, ballot-compact into LDS segment, prefix-merge, coalesced list
// store. W->Wt transpose-cast distributed over blocks 16..31 (one wave per
// n; the single-block version was a ~25us serialized straggler, R16 -9us).
// Six scan structures all plateau at ~2.5 TB/s effective A-read (~83% of
// the per-direction read rate implied by the 6.3 TB/s copy ubench).
// ---------------------------------------------------------------------------
__global__ __launch_bounds__(512) void scan_k(const float* __restrict__ A,
                                              const float* __restrict__ W,
                                              unsigned short* __restrict__ nbr,
                                              int* __restrict__ deg,
                                              unsigned short* __restrict__ Wt) {
    __shared__ unsigned short seg[8 * 64];
    __shared__ int scnt[8];

    int tid = threadIdx.x;
    int lane = tid & 63;
    int w = tid >> 6;            // 0..7
    int i = blockIdx.x;

    {
        const float4* ar = (const float4*)(A + (size_t)i * N_NODES);
        unsigned long long below = (1ull << lane) - 1ull;
        float4 v0 = ar[w * 128 + lane];
        float4 v1 = ar[w * 128 + 64 + lane];
        int cnt = 0;
#define SCAN4(vv, base)                                                         \
        {                                                                       \
            bool f0 = vv.x > 0.f, f1 = vv.y > 0.f, f2 = vv.z > 0.f, f3 = vv.w > 0.f; \
            unsigned long long m0 = __ballot(f0), m1 = __ballot(f1),            \
                               m2 = __ballot(f2), m3 = __ballot(f3);            \
            int pos = cnt + (int)__popcll(m0 & below) + (int)__popcll(m1 & below) \
                          + (int)__popcll(m2 & below) + (int)__popcll(m3 & below); \
            int colb = base;                                                    \
            if (f0) { if (pos < 64) seg[w * 64 + pos] = (unsigned short)(colb);     ++pos; } \
            if (f1) { if (pos < 64) seg[w * 64 + pos] = (unsigned short)(colb + 1); ++pos; } \
            if (f2) { if (pos < 64) seg[w * 64 + pos] = (unsigned short)(colb + 2); ++pos; } \
            if (f3) { if (pos < 64) seg[w * 64 + pos] = (unsigned short)(colb + 3); ++pos; } \
            cnt += (int)__popcll(m0) + (int)__popcll(m1)                        \
                 + (int)__popcll(m2) + (int)__popcll(m3);                       \
        }
        SCAN4(v0, 4 * (w * 128 + lane))
        SCAN4(v1, 4 * (w * 128 + 64 + lane))
#undef SCAN4
        if (lane == 0) scnt[w] = cnt < 64 ? cnt : 64;
    }
    __syncthreads();

    {
        int off = 0, d = 0;
#pragma unroll
        for (int t = 0; t < 8; ++t) {
            int c = scnt[t];
            if (t < w) off += c;
            d += c;
        }
        int cw = scnt[w];
        unsigned short* lst = nbr + (size_t)i * CAP;
        if (lane < cw && off + lane < CAP) lst[off + lane] = seg[w * 64 + lane];
        if (tid == 0) deg[i] = d < CAP ? d : CAP;
    }

    // ---- distributed W transpose-cast: blocks 16..31, 8 n's each ----
    if (i >= 16 && i < 32) {
        int b = i - 16;
        int n = b * 8 + w;               // one wave per n
        int k2 = lane * 2;               // lane covers 2 k's
        float w0 = W[(size_t)k2 * FEAT + n];
        float w1 = W[(size_t)(k2 + 1) * FEAT + n];
        *(unsigned int*)(Wt + (size_t)n * FEAT + k2) = pk2bf(w0, w1);
    }
}

// ---------------------------------------------------------------------------
// K2: h = x @ Wt^T via MFMA 16x16x32 bf16, LDS-staged (R13, verified).
// x-tile coalesced f32 -> bf16 -> swizzled LDS; Wt (L2-hot) -> swizzled LDS.
// Fragment ds_reads use XOR swizzle kb ^ ((row&7)<<4) (G4; row&7 == ln&7).
// Fragment layout (gfx950, m89-verified): A/B elems 0-3 <-> k=(lane>>4)*4+j,
// elems 4-7 <-> k=16+..., m/n = lane&15; C/D col=lane&15, row=(lane>>4)*4+r.
// ---------------------------------------------------------------------------
__global__ __launch_bounds__(256) void gemm_mfma(const float* __restrict__ x,
                                                 const unsigned short* __restrict__ Wt,
                                                 const float* __restrict__ a_src,
                                                 const float* __restrict__ a_dst,
                                                 unsigned short* __restrict__ h,
                                                 float* __restrict__ es,
                                                 float* __restrict__ ed) {
    __shared__ unsigned short xs[64 * FEAT];    // 16 KB, swizzled bf16 x-tile
    __shared__ unsigned short wsh[FEAT * FEAT]; // 32 KB, swizzled bf16 Wt

    int tid = threadIdx.x;
    int lane = tid & 63;
    int w = tid >> 6;
    int ln = lane & 15;
    int kg = lane >> 4;              // 0..3
    int m0 = blockIdx.x * 64;

#pragma unroll
    for (int it = 0; it < 16; ++it) {
        int idx = it * 256 + tid;        // 0..4095
        int n = idx >> 5, c = idx & 31;  // chunk c covers kb = c*8 .. +8
        uint2 v = *(const uint2*)(Wt + (size_t)n * FEAT + c * 4);
        int kb = (c * 8) ^ ((n & 7) << 4);
        *(uint2*)((char*)wsh + n * 256 + kb) = v;
    }
#pragma unroll
    for (int it = 0; it < 8; ++it) {
        int idx = it * 256 + tid;        // 0..2047
        int r = idx >> 5, c = idx & 31;
        float4 v = *(const float4*)(x + (size_t)(m0 + r) * FEAT + c * 4);
        uint2 p; p.x = pk2bf(v.x, v.y); p.y = pk2bf(v.z, v.w);
        int kb = (c * 8) ^ ((r & 7) << 4);
        *(uint2*)((char*)xs + r * 256 + kb) = p;
    }
    __syncthreads();

    union frag { short8 s; uint u[4]; };
    int sw = (ln & 7) << 4;              // per-lane swizzle constant

    f32x4 acc[8];
#pragma unroll
    for (int t = 0; t < 8; ++t) acc[t] = (f32x4)(0.f);

    int ra = w * 16 + ln;                // a-frag LDS row
#pragma unroll
    for (int ks = 0; ks < 4; ++ks) {
        int klo = (ks * 64 + kg * 8) ^ sw;
        int khi = (ks * 64 + 32 + kg * 8) ^ sw;
        frag af;
        {
            uint2 lo = *(const uint2*)((const char*)xs + ra * 256 + klo);
            uint2 hi = *(const uint2*)((const char*)xs + ra * 256 + khi);
            af.u[0] = lo.x; af.u[1] = lo.y; af.u[2] = hi.x; af.u[3] = hi.y;
        }
#pragma unroll
        for (int t = 0; t < 8; ++t) {
            int n = t * 16 + ln;
            frag bf;
            uint2 lo = *(const uint2*)((const char*)wsh + n * 256 + klo);
            uint2 hi = *(const uint2*)((const char*)wsh + n * 256 + khi);
            bf.u[0] = lo.x; bf.u[1] = lo.y; bf.u[2] = hi.x; bf.u[3] = hi.y;
            acc[t] = __builtin_amdgcn_mfma_f32_16x16x32_bf16(af.s, bf.s, acc[t], 0, 0, 0);
        }
    }

    float as8[8], ad8[8];
#pragma unroll
    for (int t = 0; t < 8; ++t) { as8[t] = a_src[t * 16 + ln]; ad8[t] = a_dst[t * 16 + ln]; }

#pragma unroll
    for (int r = 0; r < 4; ++r) {
        int m = m0 + w * 16 + kg * 4 + r;
        float ps = 0.f, pd = 0.f;
#pragma unroll
        for (int t = 0; t < 8; ++t) {
            float vv = acc[t][r];
            h[(size_t)m * FEAT + t * 16 + ln] = f2bf(vv);
            ps += vv * as8[t];
            pd += vv * ad8[t];
        }
#pragma unroll
        for (int off = 8; off >= 1; off >>= 1) {
            ps += __shfl_xor(ps, off);
            pd += __shfl_xor(pd, off);
        }
        if (ln == 0) { es[m] = ps; ed[m] = pd; }
    }
}

// ---------------------------------------------------------------------------
// K3: aggregate: one wave per (b,i); reg-cached z/col from the max pass;
// 8 nbrs/iter (4 groups x 2 chains), 8 bf16 cols/lane as uint4, packed-f32
// FMA. blockIdx&7 = batch -> XCD/L2 affinity for the 1MB h[b] slice.
// ---------------------------------------------------------------------------
__global__ __launch_bounds__(256) void aggregate(const unsigned short* __restrict__ h,
                                                 const float* __restrict__ es,
                                                 const float* __restrict__ ed,
                                                 const unsigned short* __restrict__ nbr,
                                                 const int* __restrict__ deg,
                                                 const float* __restrict__ bias,
                                                 float* __restrict__ out) {
    int lane = threadIdx.x & 63;
    int g = lane >> 4;
    int c8 = (lane & 15) * 8;
    int b = blockIdx.x & 7;
    int i = (blockIdx.x >> 3) * 4 + (threadIdx.x >> 6);

    int d = deg[i];
    const unsigned short* lst = nbr + (size_t)i * CAP;
    float esv = es[b * N_NODES + i];
    const float* edb = ed + b * N_NODES;

    float zv0 = -1e30f, zv1 = -1e30f, zv2 = -1e30f, zv3 = -1e30f;
    int cv0 = 0, cv1 = 0, cv2 = 0, cv3 = 0;
    float m = -1e30f;
#define PASS1(c, zz, cc)                                            \
    if (c * 64 < d) {                                               \
        int j = c * 64 + lane;                                      \
        if (j < d) {                                                \
            cc = lst[j];                                            \
            float z0 = esv + edb[cc];                               \
            zz = z0 > 0.f ? z0 : 0.2f * z0;                         \
        }                                                           \
        m = fmaxf(m, zz);                                           \
    }
    PASS1(0, zv0, cv0)
    PASS1(1, zv1, cv1)
    PASS1(2, zv2, cv2)
    PASS1(3, zv3, cv3)
#undef PASS1
#pragma unroll
    for (int off = 32; off >= 1; off >>= 1) m = fmaxf(m, __shfl_xor(m, off));

    const unsigned short* hb = h + (size_t)b * N_NODES * FEAT;
    v2f acc0[4], acc1[4];
#pragma unroll
    for (int k = 0; k < 4; ++k) { acc0[k] = (v2f)(0.f); acc1[k] = (v2f)(0.f); }
    float s = 0.f;
#define PASS2(c, zz, cc)                                                        \
    if (c * 64 < d) {                                                           \
        float p = __expf(zz - m);                                               \
        s += p;                                                                 \
        int n = d - c * 64; if (n > 64) n = 64;                                 \
        int nn = (n + 7) & ~7;                                                  \
        for (int jj = 0; jj < nn; jj += 8) {                                    \
            int j0 = jj + g, j1 = jj + 4 + g;                                   \
            float p0 = __shfl(p, j0); int cj0 = __shfl(cc, j0);                 \
            float p1 = __shfl(p, j1); int cj1 = __shfl(cc, j1);                 \
            uint4 h0 = *(const uint4*)(hb + (size_t)cj0 * FEAT + c8);           \
            uint4 h1 = *(const uint4*)(hb + (size_t)cj1 * FEAT + c8);           \
            v2f pp0; pp0[0] = p0; pp0[1] = p0;                                  \
            v2f pp1; pp1[0] = p1; pp1[1] = p1;                                  \
            fma8v(acc0, pp0, h0);                                               \
            fma8v(acc1, pp1, h1);                                               \
        }                                                                       \
    }
    PASS2(0, zv0, cv0)
    PASS2(1, zv1, cv1)
    PASS2(2, zv2, cv2)
    PASS2(3, zv3, cv3)
#undef PASS2

#pragma unroll
    for (int off = 32; off >= 1; off >>= 1) s += __shfl_xor(s, off);
    float inv = 1.0f / s;

#pragma unroll
    for (int k = 0; k < 4; ++k) acc0[k] += acc1[k];
#pragma unroll
    for (int k = 0; k < 4; ++k) {
        acc0[k][0] += __shfl_xor(acc0[k][0], 16);
        acc0[k][1] += __shfl_xor(acc0[k][1], 16);
        acc0[k][0] += __shfl_xor(acc0[k][0], 32);
        acc0[k][1] += __shfl_xor(acc0[k][1], 32);
    }

    if (lane < 16) {
        float4 b0 = *(const float4*)(bias + c8);
        float4 b1 = *(const float4*)(bias + c8 + 4);
        float o[8];
        o[0] = acc0[0][0] * inv + b0.x; o[1] = acc0[0][1] * inv + b0.y;
        o[2] = acc0[1][0] * inv + b0.z; o[3] = acc0[1][1] * inv + b0.w;
        o[4] = acc0[2][0] * inv + b1.x; o[5] = acc0[2][1] * inv + b1.y;
        o[6] = acc0[3][0] * inv + b1.z; o[7] = acc0[3][1] * inv + b1.w;
#pragma unroll
        for (int k = 0; k < 8; ++k) o[k] = o[k] > 0.f ? o[k] : 0.3f * o[k];
        float* orow = out + ((size_t)b * N_NODES + i) * FEAT + c8;
        *(float4*)orow = make_float4(o[0], o[1], o[2], o[3]);
        *(float4*)(orow + 4) = make_float4(o[4], o[5], o[6], o[7]);
    }
}

// ---------------------------------------------------------------------------
extern "C" void kernel_launch(void* const* d_in, const int* in_sizes, int n_in,
                              void* d_out, int out_size, void* d_ws, size_t ws_size,
                              hipStream_t stream) {
    const float* x     = (const float*)d_in[0];
    const float* A     = (const float*)d_in[1];
    const float* W     = (const float*)d_in[2];
    const float* bias  = (const float*)d_in[3];
    const float* a_src = (const float*)d_in[4];
    const float* a_dst = (const float*)d_in[5];
    float* out = (float*)d_out;

    // workspace layout (~10.9 MB)
    char* ws = (char*)d_ws;
    unsigned short* h  = (unsigned short*)ws;                   // B*N*C bf16 (8.39 MB)
    float* es = (float*)(h + (size_t)BATCH * N_NODES * FEAT);   // B*N f32
    float* ed = es + BATCH * N_NODES;                           // B*N f32
    unsigned short* Wt = (unsigned short*)(ed + BATCH * N_NODES); // F*C bf16 (32 KB)
    int* dg = (int*)(Wt + FEAT * FEAT);                         // N ints
    unsigned short* nb = (unsigned short*)(dg + N_NODES);       // N*CAP (2 MB)

    hipLaunchKernelGGL(scan_k, dim3(N_NODES), dim3(512), 0, stream,
                       A, W, nb, dg, Wt);
    hipLaunchKernelGGL(gemm_mfma, dim3(BATCH * N_NODES / 64), dim3(256), 0, stream,
                       x, Wt, a_src, a_dst, h, es, ed);
    hipLaunchKernelGGL(aggregate, dim3(BATCH * N_NODES / 4), dim3(256), 0, stream,
                       h, es, ed, nb, dg, bias, out);
}